// Round 12
// baseline (336.191 us; speedup 1.0000x reference)
//
#include <hip/hip_runtime.h>
#include <hip/hip_bf16.h>

#define BB 16384
#define TT 10
#define NLAB 500

typedef __attribute__((ext_vector_type(8))) __bf16 bf16x8;
typedef __attribute__((ext_vector_type(4))) float f32x4;
typedef __attribute__((ext_vector_type(8))) short short8v;

__device__ __forceinline__ unsigned short f2bf(float f) {
  union { float f; unsigned int u; } x; x.f = f;
  unsigned int r = 0x7fffu + ((x.u >> 16) & 1u);
  return (unsigned short)((x.u + r) >> 16);
}

// raw v_exp_f32 / v_rcp_f32 — avoids OCML denorm-guard fixups (range here is O(1))
__device__ __forceinline__ float sigm(float x) {
  return __builtin_amdgcn_rcpf(1.f + __builtin_amdgcn_exp2f(-1.4426950408889634f * x));
}
// tanh(x) = 2*sigm(2x) - 1: 5 ops, exact at +-inf
__device__ __forceinline__ float tanh_(float x) {
  float e = __builtin_amdgcn_exp2f(-2.8853900817779268f * x);   // exp(-2x)
  return 2.f * __builtin_amdgcn_rcpf(1.f + e) - 1.f;
}

// async global->LDS, 16B per lane; global src is PER-LANE, LDS dest = uniform base + lane*16
__device__ __forceinline__ void gload_lds16(const unsigned short* g, unsigned short* l) {
  __builtin_amdgcn_global_load_lds(
      (const __attribute__((address_space(1))) unsigned int*)g,
      (__attribute__((address_space(3))) unsigned int*)l, 16, 0, 0);
}

#define SCHED0() __builtin_amdgcn_sched_barrier(0)
// lgkm-only barrier: LDS read/write visibility, but vmem (weight prefetch) stays in flight
#define BAR_LGKM()                                                       \
  { SCHED0(); asm volatile("s_waitcnt lgkmcnt(0)" ::: "memory");         \
    __builtin_amdgcn_s_barrier(); SCHED0(); }
// + vmcnt(8): exactly the 8 cross-pass bc/bn loads outstanding -> older xts gload retired
#define BAR_LGKM_VM8()                                                   \
  { SCHED0(); asm volatile("s_waitcnt vmcnt(8) lgkmcnt(0)" ::: "memory");\
    __builtin_amdgcn_s_barrier(); SCHED0(); }

// ---------------- weight/bias prep: SEQUENTIAL chunk layout ----------------
// 60 chunks x 16384 elems, each chunk [wid(8)][frag(4)][lane(64)][e(8)].
// Consumption order per t == memory order:
//   c  0..9  : L0 pass IF  (gates i,f), ks=c      K: ks*32 (k<64 = x, else h1)
//   c 10..19 : L0 pass GO  (gates g,o)
//   c 20..27 : L1 IF, h2-half (Whh1), ks=c-20
//   c 28..35 : L1 IF, h1-half (Wih1)
//   c 36..43 : L1 GO, h2-half
//   c 44..51 : L1 GO, h1-half
//   c 52..59 : Wout, ks=c-52, cols = wid*64 + frag*16
__global__ void prep_w(const float* __restrict__ Wih0, const float* __restrict__ Whh0,
                       const float* __restrict__ bih0, const float* __restrict__ bhh0,
                       const float* __restrict__ Wih1, const float* __restrict__ Whh1,
                       const float* __restrict__ bih1, const float* __restrict__ bhh1,
                       const float* __restrict__ Wout, const float* __restrict__ bout,
                       unsigned short* __restrict__ wall, float* __restrict__ bblob) {
  int i = blockIdx.x * 256 + threadIdx.x;
  if (i < 983040) {
    int c = i >> 14, r = i & 16383;
    int wid = r >> 11, frag = (r >> 9) & 3, lane = (r >> 3) & 63, e = r & 7;
    int kin = ((lane >> 4) << 3) + e;
    float v;
    if (c < 20) {                        // L0
      int pass = c / 10, ks = c % 10;
      int n = (pass * 2 + (frag >> 1)) * 256 + wid * 32 + (frag & 1) * 16 + (lane & 15);
      int k = ks * 32 + kin;
      if (k < 64) v = (k < 39) ? Wih0[n * 39 + k] : 0.f;
      else        v = Whh0[n * 256 + (k - 64)];
    } else if (c < 52) {                 // L1
      int idx = c - 20;
      int pass = idx >> 4, half = (idx >> 3) & 1, ks = idx & 7;
      int n = (pass * 2 + (frag >> 1)) * 256 + wid * 32 + (frag & 1) * 16 + (lane & 15);
      int k = ks * 32 + kin;
      v = half ? Wih1[n * 256 + k]       // h1-half: input weights
               : Whh1[n * 256 + k];      // h2-half: recurrent weights
    } else {                             // Wout
      int ks = c - 52;
      int n = wid * 64 + frag * 16 + (lane & 15);
      int k = ks * 32 + kin;
      v = (n < NLAB) ? Wout[n * 256 + k] : 0.f;
    }
    wall[i] = f2bf(v);
  } else {                               // bias blob: 2560 f32 used
    int j = i - 983040;
    if (j < 1024)       bblob[j] = bih0[j] + bhh0[j];
    else if (j < 2048)  bblob[j] = bih1[j - 1024] + bhh1[j - 1024];
    else if (j < 2560) { int n = j - 2048; bblob[j] = (n < NLAB) ? bout[n] : 0.f; }
  }
}

// ---------------- embedding gather -> x in A-frag-linear layout ----------------
// xfrag: [tile(256)][t(10)][kc(2)][rb(4)][lane(64)][8] bf16
__global__ void gather_x(const int* __restrict__ car_idx, const int* __restrict__ region_idx,
                         const int* __restrict__ poi_idx, const int* __restrict__ week_idx,
                         const int* __restrict__ time_idx,
                         const float* __restrict__ car_emb, const float* __restrict__ region_emb,
                         const float* __restrict__ poi_emb, const float* __restrict__ week_emb,
                         const float* __restrict__ time_emb,
                         unsigned short* __restrict__ xfrag) {
  int tid = blockIdx.x * 256 + threadIdx.x;
  if (tid >= BB * TT) return;
  int t = tid / BB;
  int b = tid - t * BB;
  int ii = b * TT + t;
  float v[64];
#pragma unroll
  for (int k = 0; k < 64; ++k) v[k] = 0.f;
  { const float* p = car_emb + (size_t)car_idx[ii] * 16;
#pragma unroll
    for (int k = 0; k < 16; ++k) v[k] = p[k]; }
  { const float* p = region_emb + (size_t)region_idx[ii] * 8;
#pragma unroll
    for (int k = 0; k < 8; ++k) v[16 + k] = p[k]; }
  { const float* p = poi_emb + (size_t)poi_idx[ii] * 4;
#pragma unroll
    for (int k = 0; k < 4; ++k) v[24 + k] = p[k]; }
  { const float* p = week_emb + (size_t)week_idx[ii] * 3;
#pragma unroll
    for (int k = 0; k < 3; ++k) v[28 + k] = p[k]; }
  { const float* p = time_emb + (size_t)time_idx[ii] * 8;
#pragma unroll
    for (int k = 0; k < 8; ++k) v[31 + k] = p[k]; }

  int tile = b >> 6, rb = (b >> 4) & 3, lrow = b & 15;
  size_t base = ((size_t)tile * TT + t) * 4096;
#pragma unroll
  for (int c = 0; c < 8; ++c) {
    int kc = c >> 2;
    int lane = lrow + ((c & 3) << 4);
    size_t off = base + (size_t)((((kc << 2) + rb) << 6) + lane) * 8;
    short8v s;
#pragma unroll
    for (int e = 0; e < 8; ++e) s[e] = (short)f2bf(v[c * 8 + e]);
    *(short8v*)(xfrag + off) = s;
  }
}

// ---------------- fused LSTM: per-wave register-streamed weights, 2-pass gates ----------------
__device__ __forceinline__ f32x4 MF(bf16x8 a, bf16x8 b, f32x4 c) {
  return __builtin_amdgcn_mfma_f32_16x16x32_bf16(a, b, c, 0, 0, 0);
}

// One GEMM pass of NKS (even) ksteps. COPY-FREE depth-2 B prefetch: 4-kstep
// unrolled body, 4 named buffers (bc,bn | b2,b3) alternate roles between
// halves -> each load issues ~1 full body (~310 cyc) before its MFMA use,
// covering L2 latency (~200-280 cyc). Invariant: bc,bn enter holding ks0,ks1
// of THIS pass (loaded long ago); exit holding ks0,ks1 of the pass at wnext.
template <int NKS, int SPLIT>
__device__ __forceinline__ void gemm_pass(f32x4 (&acc)[2][2][4],
    bf16x8 (&bc)[4], bf16x8 (&bn)[4],
    const unsigned short* wp, const unsigned short* wnext,
    const unsigned short* ab1, const unsigned short* ab2, int lane) {
#define AADDR(KS) \
  ((SPLIT < NKS && (KS) >= SPLIT) ? (ab2 + ((KS) - SPLIT) * 2048) : (ab1 + (KS) * 2048))
#define MFMA16(AREG, BREG)                                              \
  { __builtin_amdgcn_s_setprio(1);                                     \
    _Pragma("unroll")                                                   \
    for (int gl = 0; gl < 2; ++gl)                                      \
      _Pragma("unroll")                                                 \
      for (int nb = 0; nb < 2; ++nb)                                    \
        _Pragma("unroll")                                               \
        for (int rb = 0; rb < 4; ++rb)                                  \
          acc[gl][nb][rb] = MF(AREG[rb], BREG[gl * 2 + nb], acc[gl][nb][rb]); \
    __builtin_amdgcn_s_setprio(0); }

  bf16x8 a0[4], a1[4];
  {
    const unsigned short* ap = AADDR(0);
#pragma unroll
    for (int rb = 0; rb < 4; ++rb) a0[rb] = *(const bf16x8*)(ap + rb * 512 + lane * 8);
  }
  bf16x8 b2[4], b3[4];
#pragma unroll 1
  for (int j = 0; j + 3 < NKS; j += 4) {
    // half 1: issue B(j+2), B(j+3); compute ks j (bc), j+1 (bn)
    {
      const unsigned short* s2 = wp + 2 * 16384;
      const unsigned short* s3 = wp + 3 * 16384;
#pragma unroll
      for (int f = 0; f < 4; ++f) b2[f] = *(const bf16x8*)(s2 + f * 512);
#pragma unroll
      for (int f = 0; f < 4; ++f) b3[f] = *(const bf16x8*)(s3 + f * 512);
    }
    {
      const unsigned short* ap = AADDR(j + 1);
#pragma unroll
      for (int rb = 0; rb < 4; ++rb) a1[rb] = *(const bf16x8*)(ap + rb * 512 + lane * 8);
    }
    MFMA16(a0, bc)
    {
      const unsigned short* ap = AADDR(j + 2);
#pragma unroll
      for (int rb = 0; rb < 4; ++rb) a0[rb] = *(const bf16x8*)(ap + rb * 512 + lane * 8);
    }
    MFMA16(a1, bn)
    // half 2: issue B(j+4), B(j+5) (or wnext ks0/ks1); compute ks j+2 (b2), j+3 (b3)
    {
      const unsigned short* s4 = (j + 4 < NKS) ? (wp + 4 * 16384) : wnext;
      const unsigned short* s5 = (j + 5 < NKS) ? (wp + 5 * 16384)
                               : ((j + 4 < NKS) ? wnext : (wnext + 16384));
#pragma unroll
      for (int f = 0; f < 4; ++f) bc[f] = *(const bf16x8*)(s4 + f * 512);
#pragma unroll
      for (int f = 0; f < 4; ++f) bn[f] = *(const bf16x8*)(s5 + f * 512);
    }
    {
      const unsigned short* ap = AADDR(j + 3);
#pragma unroll
      for (int rb = 0; rb < 4; ++rb) a1[rb] = *(const bf16x8*)(ap + rb * 512 + lane * 8);
    }
    MFMA16(a0, b2)
    {
      const unsigned short* ap = AADDR((j + 4 < NKS) ? (j + 4) : (NKS - 1));
#pragma unroll
      for (int rb = 0; rb < 4; ++rb) a0[rb] = *(const bf16x8*)(ap + rb * 512 + lane * 8);
    }
    MFMA16(a1, b3)
    wp += 4 * 16384;
  }
  if (NKS % 4) {  // tail pair: bc,bn hold ks NKS-2, NKS-1 (loaded >=1 body ago)
    {
      const unsigned short* ap = AADDR(NKS - 1);
#pragma unroll
      for (int rb = 0; rb < 4; ++rb) a1[rb] = *(const bf16x8*)(ap + rb * 512 + lane * 8);
    }
    MFMA16(a0, bc)
    MFMA16(a1, bn)
    // reload bc,bn with wnext ks0,ks1 (WAR on regs after MFMA issue: compiler-safe;
    // next use is across cell-update/barriers -> latency fully covered)
#pragma unroll
    for (int f = 0; f < 4; ++f) bc[f] = *(const bf16x8*)(wnext + f * 512);
#pragma unroll
    for (int f = 0; f < 4; ++f) bn[f] = *(const bf16x8*)(wnext + 16384 + f * 512);
  }
#undef MFMA16
#undef AADDR
}

// after IF pass: LDS si-slot <- sigm(i); c-slot <- sigm(f) * c (frees acc regs)
// si slots are per-thread (same lane writes & reads) -> no barrier needed.
__device__ __forceinline__ void partial_if(f32x4 (&acc)[2][2][4], f32x4 (&cst)[2][4],
                                           float* sib) {
#pragma unroll
  for (int nb = 0; nb < 2; ++nb)
#pragma unroll
    for (int rb = 0; rb < 4; ++rb)
#pragma unroll
      for (int r = 0; r < 4; ++r) {
        sib[((nb << 4) + (rb << 2) + r) << 6] = sigm(acc[0][nb][rb][r]);
        cst[nb][rb][r] = sigm(acc[1][nb][rb][r]) * cst[nb][rb][r];
      }
}

// after GO pass: c = pf + si*tanh(g); h = sigm(o)*tanh(c) -> bf16 A-frag write
__device__ __forceinline__ void finish_go(f32x4 (&acc)[2][2][4], f32x4 (&cst)[2][4],
    const float* sib, unsigned short* hbuf, int lane, int wid) {
  int lrow = ((lane >> 4) << 2);
  int l15 = lane & 15;
#pragma unroll
  for (int nb = 0; nb < 2; ++nb) {
    int jw = (nb << 4) + l15;
    int lane_dst_base = ((jw >> 3) << 4);
    int elem = jw & 7;
#pragma unroll
    for (int rb = 0; rb < 4; ++rb)
#pragma unroll
      for (int r = 0; r < 4; ++r) {
        float g = tanh_(acc[0][nb][rb][r]);
        float o = sigm(acc[1][nb][rb][r]);
        float c = cst[nb][rb][r] + sib[((nb << 4) + (rb << 2) + r) << 6] * g;
        cst[nb][rb][r] = c;
        float h = o * tanh_(c);
        int lane_dst = lrow + r + lane_dst_base;
        hbuf[(size_t)((((wid << 2) + rb) << 6) + lane_dst) * 8 + elem] = f2bf(h);
      }
  }
}

__global__ __launch_bounds__(512, 1) void lstm_fused(
    const unsigned short* __restrict__ xfrag, const unsigned short* __restrict__ wall,
    const float* __restrict__ bblob, float* __restrict__ out) {
  __shared__ __align__(16) unsigned short h1s[16384];   // 32 KB [kc8][rb4][lane64][8]
  __shared__ __align__(16) unsigned short h2s[16384];   // 32 KB
  __shared__ __align__(16) unsigned short xts[4096];    // 8 KB [kc2][rb4][lane64][8]
  __shared__ __align__(16) float bls[2560];             // 10 KB biases
  __shared__ __align__(16) float sis[16384];            // 64 KB per-thread si slots (f32)

  int tid = threadIdx.x, lane = tid & 63, wid = tid >> 6;
  int tile = blockIdx.x, b0 = tile << 6, l15 = lane & 15;

  // no h zero-init needed: t=0 skips all h-GEMMs and finish_go fully writes h1s/h2s
  for (int i = tid; i < 2560; i += 512) bls[i] = bblob[i];
  gload_lds16(xfrag + (size_t)(tile * TT) * 4096 + wid * 512 + lane * 8, xts + wid * 512);

  // per-thread si base: slot v at sib[v<<6], v = (nb<<4)+(rb<<2)+r
  float* sib = sis + (wid << 11) + lane;

  // single per-wave weight base; pass bases = wb + chunk0*16384
  const unsigned short* wb = wall + wid * 2048 + lane * 8;

  bf16x8 bc[4], bn[4];
#pragma unroll
  for (int f = 0; f < 4; ++f) bc[f] = *(const bf16x8*)(wb + f * 512);
#pragma unroll
  for (int f = 0; f < 4; ++f) bn[f] = *(const bf16x8*)(wb + 16384 + f * 512);

  asm volatile("s_waitcnt vmcnt(0)" ::: "memory");   // x0 + bc/bn visible (once)
  __syncthreads();

  f32x4 c1[2][4], c2[2][4];
#pragma unroll
  for (int nb = 0; nb < 2; ++nb)
#pragma unroll
    for (int rb = 0; rb < 4; ++rb) {
      c1[nb][rb] = (f32x4){0.f, 0.f, 0.f, 0.f};
      c2[nb][rb] = (f32x4){0.f, 0.f, 0.f, 0.f};
    }
  f32x4 acc[2][2][4];

#define ACC_BIAS(BOFF, GBASE)                                                     \
  _Pragma("unroll")                                                               \
  for (int gl = 0; gl < 2; ++gl)                                                  \
    _Pragma("unroll")                                                             \
    for (int nb = 0; nb < 2; ++nb) {                                              \
      float bv = bls[(BOFF) + (((GBASE) + gl) << 8) + (wid << 5) + (nb << 4) + l15]; \
      _Pragma("unroll")                                                           \
      for (int rb = 0; rb < 4; ++rb) acc[gl][nb][rb] = (f32x4){bv, bv, bv, bv};   \
    }

  // ======== t = 0: h1(-1)=h2(-1)=0 -> only x-chunks of L0, h1-half of L1 ========
  ACC_BIAS(0, 0)
  gemm_pass<2, 2>(acc, bc, bn, wb, wb + 163840, xts, xts, lane);           // chunks 0..1
  partial_if(acc, c1, sib);
  ACC_BIAS(0, 2)
  gemm_pass<2, 2>(acc, bc, bn, wb + 163840, wb + 458752, xts, xts, lane);  // chunks 10..11
  BAR_LGKM()                                       // xts reads done
  gload_lds16(xfrag + (size_t)(tile * TT + 1) * 4096 + wid * 512 + lane * 8,
              xts + wid * 512);
  finish_go(acc, c1, sib, h1s, lane, wid);         // writes ALL of h1s
  ACC_BIAS(1024, 0)
  BAR_LGKM()                                       // h1s writes visible
  gemm_pass<8, 8>(acc, bc, bn, wb + 458752, wb + 720896, h1s, h1s, lane);  // chunks 28..35
  partial_if(acc, c2, sib);
  ACC_BIAS(1024, 2)
  gemm_pass<8, 8>(acc, bc, bn, wb + 720896, wb, h1s, h1s, lane);           // chunks 44..51
  BAR_LGKM_VM8()                                   // h1s reads done; xts(t=1) landed
  finish_go(acc, c2, sib, h2s, lane, wid);         // writes ALL of h2s

  // ======== t = 1..9: full recurrence ========
#pragma unroll 1
  for (int t = 1; t < TT; ++t) {
    // ---- layer 0, pass IF: [x_t | h1] @ W0[i,f]^T     (chunks 0..9)
    ACC_BIAS(0, 0)
    gemm_pass<10, 2>(acc, bc, bn, wb, wb + 163840, xts, h1s, lane);
    partial_if(acc, c1, sib);
    // ---- layer 0, pass GO                              (chunks 10..19)
    ACC_BIAS(0, 2)
    gemm_pass<10, 2>(acc, bc, bn, wb + 163840, wb + 327680, xts, h1s, lane);
    BAR_LGKM()                                     // B1: xts/h1s reads done; bc/bn prefetch in flight
    if (t < TT - 1)
      gload_lds16(xfrag + (size_t)(tile * TT + t + 1) * 4096 + wid * 512 + lane * 8,
                  xts + wid * 512);
    finish_go(acc, c1, sib, h1s, lane, wid);       // writes h1s
    // ---- layer 1, pass IF: h2-half first               (chunks 20..27)
    ACC_BIAS(1024, 0)
    gemm_pass<8, 8>(acc, bc, bn, wb + 327680, wb + 458752, h2s, h2s, lane);
    BAR_LGKM()                                     // B2: h1s writes visible
    gemm_pass<8, 8>(acc, bc, bn, wb + 458752, wb + 589824, h1s, h1s, lane);  // 28..35
    partial_if(acc, c2, sib);
    // ---- layer 1, pass GO: merged h2+h1 halves          (chunks 36..51)
    ACC_BIAS(1024, 2)
    gemm_pass<16, 8>(acc, bc, bn, wb + 589824,
                     (t < TT - 1) ? wb : (wb + 851968), h2s, h1s, lane);
    BAR_LGKM_VM8()                                 // B3: h reads done; vmcnt(8)=bc/bn only -> xts landed
    finish_go(acc, c2, sib, h2s, lane, wid);       // writes h2s
  }
  BAR_LGKM()                                       // final h2s visible

  // ---- output projection: out = h2 @ Wout^T + bout     (chunks 52..59)
#pragma unroll
  for (int gl = 0; gl < 2; ++gl)
#pragma unroll
    for (int nb = 0; nb < 2; ++nb) {
      float bv = bls[2048 + (wid << 6) + ((gl * 2 + nb) << 4) + l15];
#pragma unroll
      for (int rb = 0; rb < 4; ++rb) acc[gl][nb][rb] = (f32x4){bv, bv, bv, bv};
    }
  gemm_pass<8, 8>(acc, bc, bn, wb + 851968, wb + 851968, h2s, h2s, lane);

#pragma unroll
  for (int gl = 0; gl < 2; ++gl)
#pragma unroll
    for (int nb = 0; nb < 2; ++nb) {
      int n = (wid << 6) + ((gl * 2 + nb) << 4) + l15;
      if (n < NLAB) {
#pragma unroll
        for (int rb = 0; rb < 4; ++rb)
#pragma unroll
          for (int r = 0; r < 4; ++r) {
            int row = (rb << 4) + ((lane >> 4) << 2) + r;
            out[(size_t)(b0 + row) * NLAB + n] = acc[gl][nb][rb][r];
          }
      }
    }
#undef ACC_BIAS
}

extern "C" void kernel_launch(void* const* d_in, const int* in_sizes, int n_in,
                              void* d_out, int out_size, void* d_ws, size_t ws_size,
                              hipStream_t stream) {
  const int* car_idx    = (const int*)d_in[0];
  const int* region_idx = (const int*)d_in[1];
  const int* poi_idx    = (const int*)d_in[2];
  const int* week_idx   = (const int*)d_in[3];
  const int* time_idx   = (const int*)d_in[4];
  const float* car_emb    = (const float*)d_in[5];
  const float* region_emb = (const float*)d_in[6];
  const float* poi_emb    = (const float*)d_in[7];
  const float* week_emb   = (const float*)d_in[8];
  const float* time_emb   = (const float*)d_in[9];
  const float* Wih0 = (const float*)d_in[10];
  const float* Whh0 = (const float*)d_in[11];
  const float* bih0 = (const float*)d_in[12];
  const float* bhh0 = (const float*)d_in[13];
  const float* Wih1 = (const float*)d_in[14];
  const float* Whh1 = (const float*)d_in[15];
  const float* bih1 = (const float*)d_in[16];
  const float* bhh1 = (const float*)d_in[17];
  const float* Wout = (const float*)d_in[18];
  const float* bout = (const float*)d_in[19];

  // workspace: xfrag (20 MB), weight wall (983040 bf16), bias blob
  unsigned short* xfrag = (unsigned short*)d_ws;       // 10,485,760 bf16
  unsigned short* wallp = xfrag + 10485760;            // 983,040 bf16
  float* bblob = (float*)(wallp + 983040);             // 2,560 f32

  prep_w<<<3850, 256, 0, stream>>>(Wih0, Whh0, bih0, bhh0, Wih1, Whh1, bih1, bhh1,
                                   Wout, bout, wallp, bblob);
  gather_x<<<640, 256, 0, stream>>>(car_idx, region_idx, poi_idx, week_idx, time_idx,
                                    car_emb, region_emb, poi_emb, week_emb, time_emb, xfrag);
  lstm_fused<<<256, 512, 0, stream>>>(xfrag, wallp, bblob, (float*)d_out);
}

// Round 13
// 304.507 us; speedup vs baseline: 1.1040x; 1.1040x over previous
//
#include <hip/hip_runtime.h>
#include <hip/hip_bf16.h>

#define BB 16384
#define TT 10
#define NLAB 500

typedef __attribute__((ext_vector_type(8))) __bf16 bf16x8;
typedef __attribute__((ext_vector_type(16))) float f32x16;
typedef __attribute__((ext_vector_type(8))) short short8v;

__device__ __forceinline__ unsigned short f2bf(float f) {
  union { float f; unsigned int u; } x; x.f = f;
  unsigned int r = 0x7fffu + ((x.u >> 16) & 1u);
  return (unsigned short)((x.u + r) >> 16);
}

// raw v_exp_f32 / v_rcp_f32 — avoids OCML denorm-guard fixups (range here is O(1))
__device__ __forceinline__ float sigm(float x) {
  return __builtin_amdgcn_rcpf(1.f + __builtin_amdgcn_exp2f(-1.4426950408889634f * x));
}
// tanh(x) = 2*sigm(2x) - 1: 5 ops, exact at +-inf
__device__ __forceinline__ float tanh_(float x) {
  float e = __builtin_amdgcn_exp2f(-2.8853900817779268f * x);   // exp(-2x)
  return 2.f * __builtin_amdgcn_rcpf(1.f + e) - 1.f;
}

// async global->LDS, 16B per lane; global src is PER-LANE, LDS dest = uniform base + lane*16
__device__ __forceinline__ void gload_lds16(const unsigned short* g, unsigned short* l) {
  __builtin_amdgcn_global_load_lds(
      (const __attribute__((address_space(1))) unsigned int*)g,
      (__attribute__((address_space(3))) unsigned int*)l, 16, 0, 0);
}

#define SCHED0() __builtin_amdgcn_sched_barrier(0)
// lgkm-only barrier: LDS read/write visibility, vmem (weight prefetch) stays in flight
#define BAR_LGKM()                                                       \
  { SCHED0(); asm volatile("s_waitcnt lgkmcnt(0)" ::: "memory");         \
    __builtin_amdgcn_s_barrier(); SCHED0(); }
// + vmcnt(4): exactly the 4 cross-pass bc loads outstanding -> older xts gload retired
#define BAR_LGKM_VM4()                                                   \
  { SCHED0(); asm volatile("s_waitcnt vmcnt(4) lgkmcnt(0)" ::: "memory");\
    __builtin_amdgcn_s_barrier(); SCHED0(); }

// ---------------- weight/bias prep: SEQUENTIAL chunk layout (32x32 frags) ----------------
// 60 chunks x 16384 elems, chunk = [wid(8)][gl(2)][kh(2)][lane(64)][e(8)].
// Element: col n = gateBase*256 + wid*32 + (lane&31); k = ks*32 + kh*16 + ((lane>>5)<<3) + e.
// Chunk order (consumption order per t == memory order):
//   c  0..9  : L0 pass IF (gates i,f)   c 10..19 : L0 pass GO (g,o)
//   c 20..27 : L1 IF h2-half (Whh1)     c 28..35 : L1 IF h1-half (Wih1)
//   c 36..43 : L1 GO h2-half            c 44..51 : L1 GO h1-half
//   c 52..59 : Wout (gl -> col-block co; n = wid*64 + co*32 + (lane&31))
__global__ void prep_w(const float* __restrict__ Wih0, const float* __restrict__ Whh0,
                       const float* __restrict__ bih0, const float* __restrict__ bhh0,
                       const float* __restrict__ Wih1, const float* __restrict__ Whh1,
                       const float* __restrict__ bih1, const float* __restrict__ bhh1,
                       const float* __restrict__ Wout, const float* __restrict__ bout,
                       unsigned short* __restrict__ wall, float* __restrict__ bblob) {
  int i = blockIdx.x * 256 + threadIdx.x;
  if (i < 983040) {
    int c = i >> 14, r = i & 16383;
    int wid = r >> 11, gl = (r >> 10) & 1, kh = (r >> 9) & 1, lane = (r >> 3) & 63, e = r & 7;
    int col = lane & 31;
    int kin = kh * 16 + ((lane >> 5) << 3) + e;
    float v;
    if (c < 20) {                        // L0
      int pass = c / 10, ks = c % 10;
      int n = (pass * 2 + gl) * 256 + wid * 32 + col;
      int k = ks * 32 + kin;
      if (k < 64) v = (k < 39) ? Wih0[n * 39 + k] : 0.f;
      else        v = Whh0[n * 256 + (k - 64)];
    } else if (c < 52) {                 // L1
      int idx = c - 20;
      int pass = idx >> 4, half = (idx >> 3) & 1, ks = idx & 7;
      int n = (pass * 2 + gl) * 256 + wid * 32 + col;
      int k = ks * 32 + kin;
      v = half ? Wih1[n * 256 + k]       // h1-half
               : Whh1[n * 256 + k];      // h2-half
    } else {                             // Wout
      int ks = c - 52;
      int n = wid * 64 + gl * 32 + col;
      int k = ks * 32 + kin;
      v = (n < NLAB) ? Wout[n * 256 + k] : 0.f;
    }
    wall[i] = f2bf(v);
  } else {                               // bias blob: 2560 f32 used
    int j = i - 983040;
    if (j < 1024)       bblob[j] = bih0[j] + bhh0[j];
    else if (j < 2048)  bblob[j] = bih1[j - 1024] + bhh1[j - 1024];
    else if (j < 2560) { int n = j - 2048; bblob[j] = (n < NLAB) ? bout[n] : 0.f; }
  }
}

// ---------------- embedding gather -> x in 32x32 A-frag layout ----------------
// xfrag: [tile(256)][t(10)][kc(2)][kh(2)][rb(2)][lane(64)][e(8)] bf16
// element (b,k): kc=k>>5, kh=(k>>4)&1, rb=(b>>5)&1, lane=(b&31)+32*((k>>3)&1), e=k&7
__global__ void gather_x(const int* __restrict__ car_idx, const int* __restrict__ region_idx,
                         const int* __restrict__ poi_idx, const int* __restrict__ week_idx,
                         const int* __restrict__ time_idx,
                         const float* __restrict__ car_emb, const float* __restrict__ region_emb,
                         const float* __restrict__ poi_emb, const float* __restrict__ week_emb,
                         const float* __restrict__ time_emb,
                         unsigned short* __restrict__ xfrag) {
  int tid = blockIdx.x * 256 + threadIdx.x;
  if (tid >= BB * TT) return;
  int t = tid / BB;
  int b = tid - t * BB;
  int ii = b * TT + t;
  float v[64];
#pragma unroll
  for (int k = 0; k < 64; ++k) v[k] = 0.f;
  { const float* p = car_emb + (size_t)car_idx[ii] * 16;
#pragma unroll
    for (int k = 0; k < 16; ++k) v[k] = p[k]; }
  { const float* p = region_emb + (size_t)region_idx[ii] * 8;
#pragma unroll
    for (int k = 0; k < 8; ++k) v[16 + k] = p[k]; }
  { const float* p = poi_emb + (size_t)poi_idx[ii] * 4;
#pragma unroll
    for (int k = 0; k < 4; ++k) v[24 + k] = p[k]; }
  { const float* p = week_emb + (size_t)week_idx[ii] * 3;
#pragma unroll
    for (int k = 0; k < 3; ++k) v[28 + k] = p[k]; }
  { const float* p = time_emb + (size_t)time_idx[ii] * 8;
#pragma unroll
    for (int k = 0; k < 8; ++k) v[31 + k] = p[k]; }

  int tile = b >> 6, rb = (b >> 5) & 1, lrow = b & 31;
  size_t base = ((size_t)tile * TT + t) * 4096;
#pragma unroll
  for (int c = 0; c < 8; ++c) {          // octet of k: k = 8c..8c+7
    int kc = c >> 2, kh = (c >> 1) & 1, kb = c & 1;
    int lane = lrow + (kb << 5);
    size_t off = base + (size_t)((((((kc << 1) + kh) << 1) + rb) << 6) + lane) * 8;
    short8v s;
#pragma unroll
    for (int e = 0; e < 8; ++e) s[e] = (short)f2bf(v[c * 8 + e]);
    *(short8v*)(xfrag + off) = s;
  }
}

// ---------------- fused LSTM: 32x32x16 MFMA, register-streamed weights ----------------
__device__ __forceinline__ f32x16 MF32(bf16x8 a, bf16x8 b, f32x16 c) {
  return __builtin_amdgcn_mfma_f32_32x32x16_bf16(a, b, c, 0, 0, 0);
}

// One GEMM pass of NKS (even) ksteps, RUNTIME loop over kstep pairs.
// Per kstep: 4 A ds_read_b128 ([kh2][rb2]) + 4 B global loads ([gl2][kh2]) + 8 MFMA
// (2x2 tiles of 32x32, 2 K-halves each). B ping-pong bc/bn (1 prefetch in flight),
// A ping-pong aA/aB. bc enters with kstep-0 frags of THIS pass, exits with
// kstep-0 frags of the pass at wnext (cross-pass prefetch).
template <int NKS, int SPLIT>
__device__ __forceinline__ void gemm_pass(f32x16 (&acc)[2][2], bf16x8 (&bc)[4],
    const unsigned short* wp, const unsigned short* wnext,
    const unsigned short* ab1, const unsigned short* ab2, int lane) {
#define AADDR(KS) \
  ((SPLIT < NKS && (KS) >= SPLIT) ? (ab2 + ((KS) - SPLIT) * 2048) : (ab1 + (KS) * 2048))
#define MFMA8(AR, BR)                                                   \
  { __builtin_amdgcn_s_setprio(1);                                     \
    _Pragma("unroll")                                                   \
    for (int kh = 0; kh < 2; ++kh)                                      \
      _Pragma("unroll")                                                 \
      for (int gl = 0; gl < 2; ++gl)                                    \
        _Pragma("unroll")                                               \
        for (int rb = 0; rb < 2; ++rb)                                  \
          acc[gl][rb] = MF32(AR[kh * 2 + rb], BR[gl * 2 + kh], acc[gl][rb]); \
    __builtin_amdgcn_s_setprio(0); }

  bf16x8 aA[4], aB[4];
  {
    const unsigned short* ap = AADDR(0);
#pragma unroll
    for (int f = 0; f < 4; ++f) aA[f] = *(const bf16x8*)(ap + f * 512 + lane * 8);
  }
#pragma unroll 1
  for (int ks = 0; ks < NKS; ks += 2) {
    // prefetch B(ks+1) and A(ks+1)
    bf16x8 bn[4];
    const unsigned short* w1 = wp + 16384;
#pragma unroll
    for (int f = 0; f < 4; ++f) bn[f] = *(const bf16x8*)(w1 + f * 512);
    const unsigned short* an = AADDR(ks + 1);
#pragma unroll
    for (int f = 0; f < 4; ++f) aB[f] = *(const bf16x8*)(an + f * 512 + lane * 8);
    // kstep ks
    MFMA8(aA, bc)
    // prefetch B(ks+2 | wnext c0) and A(ks+2, clamped dummy on last pair)
    const unsigned short* w2 = (ks + 2 < NKS) ? (wp + 32768) : wnext;
#pragma unroll
    for (int f = 0; f < 4; ++f) bc[f] = *(const bf16x8*)(w2 + f * 512);
    const unsigned short* an2 = AADDR((ks + 2 < NKS) ? (ks + 2) : (NKS - 1));
#pragma unroll
    for (int f = 0; f < 4; ++f) aA[f] = *(const bf16x8*)(an2 + f * 512 + lane * 8);
    // kstep ks+1
    MFMA8(aB, bn)
    wp += 32768;
  }
#undef MFMA8
#undef AADDR
}

// after IF pass: LDS si-slot <- sigm(i); c-slot <- sigm(f) * c (frees acc regs)
// si slots are per-thread (same lane writes & reads) -> no barrier needed.
__device__ __forceinline__ void partial_if(f32x16 (&acc)[2][2], f32x16 (&cst)[2],
                                           float* sib) {
#pragma unroll
  for (int rb = 0; rb < 2; ++rb)
#pragma unroll
    for (int r = 0; r < 16; ++r) {
      sib[((rb << 4) + r) << 6] = sigm(acc[0][rb][r]);
      cst[rb][r] = sigm(acc[1][rb][r]) * cst[rb][r];
    }
}

// after GO pass: c = pf + si*tanh(g); h = sigm(o)*tanh(c) -> bf16 write in A-frag layout.
// 32x32 C/D mapping: col = lane&31 (cell), row = (r&3) + 8*(r>>2) + 4*(lane>>5) + 32*rb.
// h-dest (b=row, k=wid*32+(lane&31)): kc=wid, kh=(lane>>4)&1, lane_dst=(row&31)+32*((lane>>3)&1), e=lane&7.
__device__ __forceinline__ void finish_go(f32x16 (&acc)[2][2], f32x16 (&cst)[2],
    const float* sib, unsigned short* hbuf, int lane, int wid) {
  int e = lane & 7;
  int kh = (lane >> 4) & 1;
  int khl = (lane >> 3) & 1;
  int rbase = (lane >> 5) << 2;
  unsigned short* base = hbuf + (wid << 11);
#pragma unroll
  for (int rb = 0; rb < 2; ++rb)
#pragma unroll
    for (int r = 0; r < 16; ++r) {
      float g = tanh_(acc[0][rb][r]);
      float o = sigm(acc[1][rb][r]);
      float c = cst[rb][r] + sib[((rb << 4) + r) << 6] * g;
      cst[rb][r] = c;
      float h = o * tanh_(c);
      int row31 = (r & 3) + ((r >> 2) << 3) + rbase;
      int lane_dst = row31 + (khl << 5);
      base[(((kh << 1) + rb) << 9) + (lane_dst << 3) + e] = f2bf(h);
    }
}

__global__ __launch_bounds__(512, 1) void lstm_fused(
    const unsigned short* __restrict__ xfrag, const unsigned short* __restrict__ wall,
    const float* __restrict__ bblob, float* __restrict__ out) {
  __shared__ __align__(16) unsigned short h1s[16384];   // 32 KB [kc8][kh2][rb2][lane64][e8]
  __shared__ __align__(16) unsigned short h2s[16384];   // 32 KB
  __shared__ __align__(16) unsigned short xts[4096];    // 8 KB [kc2][kh2][rb2][lane64][e8]
  __shared__ __align__(16) float bls[2560];             // 10 KB biases
  __shared__ __align__(16) float sis[16384];            // 64 KB per-thread si slots (f32)

  int tid = threadIdx.x, lane = tid & 63, wid = tid >> 6;
  int tile = blockIdx.x, b0 = tile << 6;
  int l31 = lane & 31;

  // no h zero-init needed: t=0 skips all h-GEMMs and finish_go fully writes h1s/h2s
  for (int i = tid; i < 2560; i += 512) bls[i] = bblob[i];
  gload_lds16(xfrag + (size_t)(tile * TT) * 4096 + wid * 512 + lane * 8, xts + wid * 512);

  // per-thread si base: slot v at sib[v<<6], v = (rb<<4)+r
  float* sib = sis + (wid << 11) + lane;

  // single per-wave weight base; pass bases = wb + chunk0*16384
  const unsigned short* wb = wall + wid * 2048 + lane * 8;

  bf16x8 bc[4];
#pragma unroll
  for (int f = 0; f < 4; ++f) bc[f] = *(const bf16x8*)(wb + f * 512);

  asm volatile("s_waitcnt vmcnt(0)" ::: "memory");   // x0 + bc visible (once)
  __syncthreads();

  f32x16 c1[2], c2[2];
#pragma unroll
  for (int rb = 0; rb < 2; ++rb)
#pragma unroll
    for (int r = 0; r < 16; ++r) { c1[rb][r] = 0.f; c2[rb][r] = 0.f; }
  f32x16 acc[2][2];

#define ACC_BIAS(BOFF, GBASE)                                                     \
  _Pragma("unroll")                                                               \
  for (int gl = 0; gl < 2; ++gl) {                                                \
    float bv = bls[(BOFF) + (((GBASE) + gl) << 8) + (wid << 5) + l31];            \
    _Pragma("unroll")                                                             \
    for (int rb = 0; rb < 2; ++rb)                                                \
      _Pragma("unroll")                                                           \
      for (int r = 0; r < 16; ++r) acc[gl][rb][r] = bv;                           \
  }

  // ======== t = 0: h1(-1)=h2(-1)=0 -> only x-chunks of L0, h1-half of L1 ========
  ACC_BIAS(0, 0)
  gemm_pass<2, 2>(acc, bc, wb, wb + 163840, xts, xts, lane);           // chunks 0..1
  partial_if(acc, c1, sib);
  ACC_BIAS(0, 2)
  gemm_pass<2, 2>(acc, bc, wb + 163840, wb + 458752, xts, xts, lane);  // chunks 10..11
  BAR_LGKM()                                       // xts reads done
  gload_lds16(xfrag + (size_t)(tile * TT + 1) * 4096 + wid * 512 + lane * 8,
              xts + wid * 512);
  finish_go(acc, c1, sib, h1s, lane, wid);         // writes ALL of h1s
  ACC_BIAS(1024, 0)
  BAR_LGKM()                                       // h1s writes visible
  gemm_pass<8, 8>(acc, bc, wb + 458752, wb + 720896, h1s, h1s, lane);  // chunks 28..35
  partial_if(acc, c2, sib);
  ACC_BIAS(1024, 2)
  gemm_pass<8, 8>(acc, bc, wb + 720896, wb, h1s, h1s, lane);           // chunks 44..51
  BAR_LGKM_VM4()                                   // h1s reads done; xts(t=1) landed
  finish_go(acc, c2, sib, h2s, lane, wid);         // writes ALL of h2s

  // ======== t = 1..9: full recurrence ========
#pragma unroll 1
  for (int t = 1; t < TT; ++t) {
    // ---- layer 0, pass IF: [x_t | h1] @ W0[i,f]^T     (chunks 0..9)
    ACC_BIAS(0, 0)
    gemm_pass<10, 2>(acc, bc, wb, wb + 163840, xts, h1s, lane);
    partial_if(acc, c1, sib);
    // ---- layer 0, pass GO                              (chunks 10..19)
    ACC_BIAS(0, 2)
    gemm_pass<10, 2>(acc, bc, wb + 163840, wb + 327680, xts, h1s, lane);
    BAR_LGKM()                                     // B1: xts/h1s reads done; bc prefetch in flight
    if (t < TT - 1)
      gload_lds16(xfrag + (size_t)(tile * TT + t + 1) * 4096 + wid * 512 + lane * 8,
                  xts + wid * 512);
    finish_go(acc, c1, sib, h1s, lane, wid);       // writes h1s
    // ---- layer 1, pass IF: h2-half first               (chunks 20..27)
    ACC_BIAS(1024, 0)
    gemm_pass<8, 8>(acc, bc, wb + 327680, wb + 458752, h2s, h2s, lane);
    BAR_LGKM()                                     // B2: h1s writes visible
    gemm_pass<8, 8>(acc, bc, wb + 458752, wb + 589824, h1s, h1s, lane);  // 28..35
    partial_if(acc, c2, sib);
    // ---- layer 1, pass GO: merged h2+h1 halves          (chunks 36..51)
    ACC_BIAS(1024, 2)
    gemm_pass<16, 8>(acc, bc, wb + 589824,
                     (t < TT - 1) ? wb : (wb + 851968), h2s, h1s, lane);
    BAR_LGKM_VM4()                                 // B3: h reads done; vmcnt(4)=bc only -> xts landed
    finish_go(acc, c2, sib, h2s, lane, wid);       // writes h2s
  }
  BAR_LGKM()                                       // final h2s visible

  // ---- output projection: out = h2 @ Wout^T + bout     (chunks 52..59)
#pragma unroll
  for (int co = 0; co < 2; ++co) {
    float bv = bls[2048 + (wid << 6) + (co << 5) + l31];
#pragma unroll
    for (int rb = 0; rb < 2; ++rb)
#pragma unroll
      for (int r = 0; r < 16; ++r) acc[co][rb][r] = bv;
  }
  gemm_pass<8, 8>(acc, bc, wb + 851968, wb + 851968, h2s, h2s, lane);

  {
    int rbase = (lane >> 5) << 2;
#pragma unroll
    for (int co = 0; co < 2; ++co) {
      int n = (wid << 6) + (co << 5) + l31;
      if (n < NLAB) {
#pragma unroll
        for (int rb = 0; rb < 2; ++rb)
#pragma unroll
          for (int r = 0; r < 16; ++r) {
            int row = (r & 3) + ((r >> 2) << 3) + rbase + (rb << 5);
            out[(size_t)(b0 + row) * NLAB + n] = acc[co][rb][r];
          }
      }
    }
  }
#undef ACC_BIAS
}

extern "C" void kernel_launch(void* const* d_in, const int* in_sizes, int n_in,
                              void* d_out, int out_size, void* d_ws, size_t ws_size,
                              hipStream_t stream) {
  const int* car_idx    = (const int*)d_in[0];
  const int* region_idx = (const int*)d_in[1];
  const int* poi_idx    = (const int*)d_in[2];
  const int* week_idx   = (const int*)d_in[3];
  const int* time_idx   = (const int*)d_in[4];
  const float* car_emb    = (const float*)d_in[5];
  const float* region_emb = (const float*)d_in[6];
  const float* poi_emb    = (const float*)d_in[7];
  const float* week_emb   = (const float*)d_in[8];
  const float* time_emb   = (const float*)d_in[9];
  const float* Wih0 = (const float*)d_in[10];
  const float* Whh0 = (const float*)d_in[11];
  const float* bih0 = (const float*)d_in[12];
  const float* bhh0 = (const float*)d_in[13];
  const float* Wih1 = (const float*)d_in[14];
  const float* Whh1 = (const float*)d_in[15];
  const float* bih1 = (const float*)d_in[16];
  const float* bhh1 = (const float*)d_in[17];
  const float* Wout = (const float*)d_in[18];
  const float* bout = (const float*)d_in[19];

  // workspace: xfrag (20 MB), weight wall (983040 bf16), bias blob
  unsigned short* xfrag = (unsigned short*)d_ws;       // 10,485,760 bf16
  unsigned short* wallp = xfrag + 10485760;            // 983,040 bf16
  float* bblob = (float*)(wallp + 983040);             // 2,560 f32

  prep_w<<<3850, 256, 0, stream>>>(Wih0, Whh0, bih0, bhh0, Wih1, Whh1, bih1, bhh1,
                                   Wout, bout, wallp, bblob);
  gather_x<<<640, 256, 0, stream>>>(car_idx, region_idx, poi_idx, week_idx, time_idx,
                                    car_emb, region_emb, poi_emb, week_emb, time_emb, xfrag);
  lstm_fused<<<256, 512, 0, stream>>>(xfrag, wallp, bblob, (float*)d_out);
}

// Round 14
// 267.816 us; speedup vs baseline: 1.2553x; 1.1370x over previous
//
#include <hip/hip_runtime.h>
#include <hip/hip_bf16.h>

#define BB 16384
#define TT 10
#define NLAB 500

typedef __attribute__((ext_vector_type(8))) __bf16 bf16x8;
typedef __attribute__((ext_vector_type(4))) float f32x4;
typedef __attribute__((ext_vector_type(8))) short short8v;

__device__ __forceinline__ unsigned short f2bf(float f) {
  union { float f; unsigned int u; } x; x.f = f;
  unsigned int r = 0x7fffu + ((x.u >> 16) & 1u);
  return (unsigned short)((x.u + r) >> 16);
}

// raw v_exp_f32 / v_rcp_f32 — avoids OCML denorm-guard fixups (range here is O(1))
__device__ __forceinline__ float sigm(float x) {
  return __builtin_amdgcn_rcpf(1.f + __builtin_amdgcn_exp2f(-1.4426950408889634f * x));
}
// tanh(x) = 2*sigm(2x) - 1: 5 ops, exact at +-inf
__device__ __forceinline__ float tanh_(float x) {
  float e = __builtin_amdgcn_exp2f(-2.8853900817779268f * x);   // exp(-2x)
  return 2.f * __builtin_amdgcn_rcpf(1.f + e) - 1.f;
}

// async global->LDS, 16B per lane; global src is PER-LANE, LDS dest = uniform base + lane*16
__device__ __forceinline__ void gload_lds16(const unsigned short* g, unsigned short* l) {
  __builtin_amdgcn_global_load_lds(
      (const __attribute__((address_space(1))) unsigned int*)g,
      (__attribute__((address_space(3))) unsigned int*)l, 16, 0, 0);
}

#define SCHED0() __builtin_amdgcn_sched_barrier(0)
// lgkm-only barrier: LDS read/write visibility, vmem (weight prefetch) stays in flight
#define BAR_LGKM()                                                       \
  { SCHED0(); asm volatile("s_waitcnt lgkmcnt(0)" ::: "memory");         \
    __builtin_amdgcn_s_barrier(); SCHED0(); }
// + vmcnt(4): exactly the 4 cross-pass bc loads outstanding -> older xts gload retired
#define BAR_LGKM_VM4()                                                   \
  { SCHED0(); asm volatile("s_waitcnt vmcnt(4) lgkmcnt(0)" ::: "memory");\
    __builtin_amdgcn_s_barrier(); SCHED0(); }

// ---------------- weight/bias prep: SEQUENTIAL chunk layout ----------------
// 60 chunks x 16384 elems, each chunk [wid(8)][frag(4)][lane(64)][e(8)].
//   c  0..9  : L0 pass IF  (gates i,f), ks=c      K: ks*32 (k<64 = x, else h1)
//   c 10..19 : L0 pass GO  (gates g,o)
//   c 20..27 : L1 IF, h2-half (Whh1), ks=c-20
//   c 28..35 : L1 IF, h1-half (Wih1)
//   c 36..43 : L1 GO, h2-half
//   c 44..51 : L1 GO, h1-half
//   c 52..59 : Wout, ks=c-52, cols = wid*64 + frag*16
__global__ void prep_w(const float* __restrict__ Wih0, const float* __restrict__ Whh0,
                       const float* __restrict__ bih0, const float* __restrict__ bhh0,
                       const float* __restrict__ Wih1, const float* __restrict__ Whh1,
                       const float* __restrict__ bih1, const float* __restrict__ bhh1,
                       const float* __restrict__ Wout, const float* __restrict__ bout,
                       unsigned short* __restrict__ wall, float* __restrict__ bblob) {
  int i = blockIdx.x * 256 + threadIdx.x;
  if (i < 983040) {
    int c = i >> 14, r = i & 16383;
    int wid = r >> 11, frag = (r >> 9) & 3, lane = (r >> 3) & 63, e = r & 7;
    int kin = ((lane >> 4) << 3) + e;
    float v;
    if (c < 20) {                        // L0
      int pass = c / 10, ks = c % 10;
      int n = (pass * 2 + (frag >> 1)) * 256 + wid * 32 + (frag & 1) * 16 + (lane & 15);
      int k = ks * 32 + kin;
      if (k < 64) v = (k < 39) ? Wih0[n * 39 + k] : 0.f;
      else        v = Whh0[n * 256 + (k - 64)];
    } else if (c < 52) {                 // L1
      int idx = c - 20;
      int pass = idx >> 4, half = (idx >> 3) & 1, ks = idx & 7;
      int n = (pass * 2 + (frag >> 1)) * 256 + wid * 32 + (frag & 1) * 16 + (lane & 15);
      int k = ks * 32 + kin;
      v = half ? Wih1[n * 256 + k]       // h1-half: input weights
               : Whh1[n * 256 + k];      // h2-half: recurrent weights
    } else {                             // Wout
      int ks = c - 52;
      int n = wid * 64 + frag * 16 + (lane & 15);
      int k = ks * 32 + kin;
      v = (n < NLAB) ? Wout[n * 256 + k] : 0.f;
    }
    wall[i] = f2bf(v);
  } else {                               // bias blob: 2560 f32 used
    int j = i - 983040;
    if (j < 1024)       bblob[j] = bih0[j] + bhh0[j];
    else if (j < 2048)  bblob[j] = bih1[j - 1024] + bhh1[j - 1024];
    else if (j < 2560) { int n = j - 2048; bblob[j] = (n < NLAB) ? bout[n] : 0.f; }
  }
}

// ---------------- embedding gather -> x in A-frag-linear layout ----------------
// xfrag: [tile(256)][t(10)][kc(2)][rb(4)][lane(64)][8] bf16
__global__ void gather_x(const int* __restrict__ car_idx, const int* __restrict__ region_idx,
                         const int* __restrict__ poi_idx, const int* __restrict__ week_idx,
                         const int* __restrict__ time_idx,
                         const float* __restrict__ car_emb, const float* __restrict__ region_emb,
                         const float* __restrict__ poi_emb, const float* __restrict__ week_emb,
                         const float* __restrict__ time_emb,
                         unsigned short* __restrict__ xfrag) {
  int tid = blockIdx.x * 256 + threadIdx.x;
  if (tid >= BB * TT) return;
  int t = tid / BB;
  int b = tid - t * BB;
  int ii = b * TT + t;
  float v[64];
#pragma unroll
  for (int k = 0; k < 64; ++k) v[k] = 0.f;
  { const float* p = car_emb + (size_t)car_idx[ii] * 16;
#pragma unroll
    for (int k = 0; k < 16; ++k) v[k] = p[k]; }
  { const float* p = region_emb + (size_t)region_idx[ii] * 8;
#pragma unroll
    for (int k = 0; k < 8; ++k) v[16 + k] = p[k]; }
  { const float* p = poi_emb + (size_t)poi_idx[ii] * 4;
#pragma unroll
    for (int k = 0; k < 4; ++k) v[24 + k] = p[k]; }
  { const float* p = week_emb + (size_t)week_idx[ii] * 3;
#pragma unroll
    for (int k = 0; k < 3; ++k) v[28 + k] = p[k]; }
  { const float* p = time_emb + (size_t)time_idx[ii] * 8;
#pragma unroll
    for (int k = 0; k < 8; ++k) v[31 + k] = p[k]; }

  int tile = b >> 6, rb = (b >> 4) & 3, lrow = b & 15;
  size_t base = ((size_t)tile * TT + t) * 4096;
#pragma unroll
  for (int c = 0; c < 8; ++c) {
    int kc = c >> 2;
    int lane = lrow + ((c & 3) << 4);
    size_t off = base + (size_t)((((kc << 2) + rb) << 6) + lane) * 8;
    short8v s;
#pragma unroll
    for (int e = 0; e < 8; ++e) s[e] = (short)f2bf(v[c * 8 + e]);
    *(short8v*)(xfrag + off) = s;
  }
}

// ---------------- fused LSTM: per-wave register-streamed weights, 2-pass gates ----------------
__device__ __forceinline__ f32x4 MF(bf16x8 a, bf16x8 b, f32x4 c) {
  return __builtin_amdgcn_mfma_f32_16x16x32_bf16(a, b, c, 0, 0, 0);
}

// One GEMM pass of NKS (even) ksteps, processed in PER-BLOCK ROTATED order:
// chunk sequence R0, R0+1, ..., NKS-1, 0, ..., R0-1. Accumulation over k is
// order-free, and the rotation de-correlates the weight-address stream across
// blocks -> spreads same-XCD CUs over L2 slices instead of hammering one.
// B ping-pong bc/bn (1 prefetch in flight) + A ping-pong aA/aB; setprio around
// MFMA clusters. bc enters holding chunk R0 of THIS pass, exits holding the
// rotated first chunk of the next pass (wnextFirst, caller-rotated).
template <int NKS, int SPLIT>
__device__ __forceinline__ void gemm_pass(f32x4 (&acc)[2][2][4], bf16x8 (&bc)[4],
    const unsigned short* wpBase, const unsigned short* wnextFirst,
    const unsigned short* ab1, const unsigned short* ab2, int R0, int lane) {
#define AADDR(J) \
  ((SPLIT < NKS && (J) >= SPLIT) ? (ab2 + ((J) - SPLIT) * 2048) : (ab1 + (J) * 2048))
#define MFMA16(AREG, BREG)                                              \
  { __builtin_amdgcn_s_setprio(1);                                     \
    _Pragma("unroll")                                                   \
    for (int gl = 0; gl < 2; ++gl)                                      \
      _Pragma("unroll")                                                 \
      for (int nb = 0; nb < 2; ++nb)                                    \
        _Pragma("unroll")                                               \
        for (int rb = 0; rb < 4; ++rb)                                  \
          acc[gl][nb][rb] = MF(AREG[rb], BREG[gl * 2 + nb], acc[gl][nb][rb]); \
    __builtin_amdgcn_s_setprio(0); }

  int j = R0;                                  // current chunk (bc holds it)
  bf16x8 aA[4], aB[4];
  {
    const unsigned short* ap = AADDR(j);
#pragma unroll
    for (int rb = 0; rb < 4; ++rb) aA[rb] = *(const bf16x8*)(ap + rb * 512 + lane * 8);
  }
#pragma unroll 1
  for (int i = 0; i < NKS; i += 2) {
    int j1 = j + 1; if (j1 == NKS) j1 = 0;
    // prefetch B(j1) and A(j1)
    bf16x8 bn[4];
    const unsigned short* w1 = wpBase + (size_t)j1 * 16384;
#pragma unroll
    for (int f = 0; f < 4; ++f) bn[f] = *(const bf16x8*)(w1 + f * 512);
    const unsigned short* an = AADDR(j1);
#pragma unroll
    for (int rb = 0; rb < 4; ++rb) aB[rb] = *(const bf16x8*)(an + rb * 512 + lane * 8);
    // logical kstep i (chunk j)
    MFMA16(aA, bc)
    // prefetch B(j2 | next-pass rotated first) and A(j2, clamped dummy on last pair)
    int j2 = j1 + 1; if (j2 == NKS) j2 = 0;
    const unsigned short* w2 = (i + 2 < NKS) ? (wpBase + (size_t)j2 * 16384) : wnextFirst;
#pragma unroll
    for (int f = 0; f < 4; ++f) bc[f] = *(const bf16x8*)(w2 + f * 512);
    const unsigned short* an2 = AADDR((i + 2 < NKS) ? j2 : j1);
#pragma unroll
    for (int rb = 0; rb < 4; ++rb) aA[rb] = *(const bf16x8*)(an2 + rb * 512 + lane * 8);
    // logical kstep i+1 (chunk j1)
    MFMA16(aB, bn)
    j = j2;
  }
#undef MFMA16
#undef AADDR
}

// after IF pass: LDS si-slot <- sigm(i); c-slot <- sigm(f) * c (frees acc regs)
// si slots are per-thread (same lane writes & reads) -> no barrier needed.
__device__ __forceinline__ void partial_if(f32x4 (&acc)[2][2][4], f32x4 (&cst)[2][4],
                                           float* sib) {
#pragma unroll
  for (int nb = 0; nb < 2; ++nb)
#pragma unroll
    for (int rb = 0; rb < 4; ++rb)
#pragma unroll
      for (int r = 0; r < 4; ++r) {
        sib[((nb << 4) + (rb << 2) + r) << 6] = sigm(acc[0][nb][rb][r]);
        cst[nb][rb][r] = sigm(acc[1][nb][rb][r]) * cst[nb][rb][r];
      }
}

// after GO pass: c = pf + si*tanh(g); h = sigm(o)*tanh(c) -> bf16 A-frag write
__device__ __forceinline__ void finish_go(f32x4 (&acc)[2][2][4], f32x4 (&cst)[2][4],
    const float* sib, unsigned short* hbuf, int lane, int wid) {
  int lrow = ((lane >> 4) << 2);
  int l15 = lane & 15;
#pragma unroll
  for (int nb = 0; nb < 2; ++nb) {
    int jw = (nb << 4) + l15;
    int lane_dst_base = ((jw >> 3) << 4);
    int elem = jw & 7;
#pragma unroll
    for (int rb = 0; rb < 4; ++rb)
#pragma unroll
      for (int r = 0; r < 4; ++r) {
        float g = tanh_(acc[0][nb][rb][r]);
        float o = sigm(acc[1][nb][rb][r]);
        float c = cst[nb][rb][r] + sib[((nb << 4) + (rb << 2) + r) << 6] * g;
        cst[nb][rb][r] = c;
        float h = o * tanh_(c);
        int lane_dst = lrow + r + lane_dst_base;
        hbuf[(size_t)((((wid << 2) + rb) << 6) + lane_dst) * 8 + elem] = f2bf(h);
      }
  }
}

__global__ __launch_bounds__(512, 1) void lstm_fused(
    const unsigned short* __restrict__ xfrag, const unsigned short* __restrict__ wall,
    const float* __restrict__ bblob, float* __restrict__ out) {
  __shared__ __align__(16) unsigned short h1s[16384];   // 32 KB [kc8][rb4][lane64][8]
  __shared__ __align__(16) unsigned short h2s[16384];   // 32 KB
  __shared__ __align__(16) unsigned short xts[4096];    // 8 KB [kc2][rb4][lane64][8]
  __shared__ __align__(16) float bls[2560];             // 10 KB biases
  __shared__ __align__(16) float sis[16384];            // 64 KB per-thread si slots (f32)

  int tid = threadIdx.x, lane = tid & 63, wid = tid >> 6;
  int tile = blockIdx.x, b0 = tile << 6, l15 = lane & 15;

  // per-block kstep rotation (varies WITHIN an XCD assuming bid%8 ~ XCD)
  int R = (tile >> 3) & 15;
  int r2 = R & 1, r8 = R & 7, r16 = R;
  int r10 = (R < 10) ? R : (R - 10);

  // no h zero-init needed: t=0 skips all h-GEMMs and finish_go fully writes h1s/h2s
  for (int i = tid; i < 2560; i += 512) bls[i] = bblob[i];
  gload_lds16(xfrag + (size_t)(tile * TT) * 4096 + wid * 512 + lane * 8, xts + wid * 512);

  // per-thread si base: slot v at sib[v<<6], v = (nb<<4)+(rb<<2)+r
  float* sib = sis + (wid << 11) + lane;

  // single per-wave weight base; pass bases = wb + chunk0*16384
  const unsigned short* wb = wall + wid * 2048 + lane * 8;

  bf16x8 bc[4];
  {
    const unsigned short* b0p = wb + (size_t)r2 * 16384;   // rotated first chunk of t=0 L0-IF
#pragma unroll
    for (int f = 0; f < 4; ++f) bc[f] = *(const bf16x8*)(b0p + f * 512);
  }

  asm volatile("s_waitcnt vmcnt(0)" ::: "memory");   // x0 + bc visible (once)
  __syncthreads();

  f32x4 c1[2][4], c2[2][4];
#pragma unroll
  for (int nb = 0; nb < 2; ++nb)
#pragma unroll
    for (int rb = 0; rb < 4; ++rb) {
      c1[nb][rb] = (f32x4){0.f, 0.f, 0.f, 0.f};
      c2[nb][rb] = (f32x4){0.f, 0.f, 0.f, 0.f};
    }
  f32x4 acc[2][2][4];

#define ACC_BIAS(BOFF, GBASE)                                                     \
  _Pragma("unroll")                                                               \
  for (int gl = 0; gl < 2; ++gl)                                                  \
    _Pragma("unroll")                                                             \
    for (int nb = 0; nb < 2; ++nb) {                                              \
      float bv = bls[(BOFF) + (((GBASE) + gl) << 8) + (wid << 5) + (nb << 4) + l15]; \
      _Pragma("unroll")                                                           \
      for (int rb = 0; rb < 4; ++rb) acc[gl][nb][rb] = (f32x4){bv, bv, bv, bv};   \
    }

  // ======== t = 0: h1(-1)=h2(-1)=0 -> only x-chunks of L0, h1-half of L1 ========
  ACC_BIAS(0, 0)
  gemm_pass<2, 2>(acc, bc, wb, wb + 163840 + (size_t)r2 * 16384, xts, xts, r2, lane);
  partial_if(acc, c1, sib);
  ACC_BIAS(0, 2)
  gemm_pass<2, 2>(acc, bc, wb + 163840, wb + 458752 + (size_t)r8 * 16384, xts, xts, r2, lane);
  BAR_LGKM()                                       // xts reads done
  gload_lds16(xfrag + (size_t)(tile * TT + 1) * 4096 + wid * 512 + lane * 8,
              xts + wid * 512);
  finish_go(acc, c1, sib, h1s, lane, wid);         // writes ALL of h1s
  ACC_BIAS(1024, 0)
  BAR_LGKM()                                       // h1s writes visible
  gemm_pass<8, 8>(acc, bc, wb + 458752, wb + 720896 + (size_t)r8 * 16384, h1s, h1s, r8, lane);
  partial_if(acc, c2, sib);
  ACC_BIAS(1024, 2)
  gemm_pass<8, 8>(acc, bc, wb + 720896, wb + (size_t)r10 * 16384, h1s, h1s, r8, lane);
  BAR_LGKM_VM4()                                   // h1s reads done; xts(t=1) landed
  finish_go(acc, c2, sib, h2s, lane, wid);         // writes ALL of h2s

  // ======== t = 1..9: full recurrence ========
#pragma unroll 1
  for (int t = 1; t < TT; ++t) {
    // ---- layer 0, pass IF: [x_t | h1] @ W0[i,f]^T     (chunks 0..9)
    ACC_BIAS(0, 0)
    gemm_pass<10, 2>(acc, bc, wb, wb + 163840 + (size_t)r10 * 16384, xts, h1s, r10, lane);
    partial_if(acc, c1, sib);
    // ---- layer 0, pass GO                              (chunks 10..19)
    ACC_BIAS(0, 2)
    gemm_pass<10, 2>(acc, bc, wb + 163840, wb + 327680 + (size_t)r8 * 16384, xts, h1s, r10, lane);
    BAR_LGKM()                                     // B1: xts/h1s reads done; bc prefetch in flight
    if (t < TT - 1)
      gload_lds16(xfrag + (size_t)(tile * TT + t + 1) * 4096 + wid * 512 + lane * 8,
                  xts + wid * 512);
    finish_go(acc, c1, sib, h1s, lane, wid);       // writes h1s
    // ---- layer 1, pass IF: h2-half first               (chunks 20..27)
    ACC_BIAS(1024, 0)
    gemm_pass<8, 8>(acc, bc, wb + 327680, wb + 458752 + (size_t)r8 * 16384, h2s, h2s, r8, lane);
    BAR_LGKM()                                     // B2: h1s writes visible
    gemm_pass<8, 8>(acc, bc, wb + 458752, wb + 589824 + (size_t)r16 * 16384, h1s, h1s, r8, lane);
    partial_if(acc, c2, sib);
    // ---- layer 1, pass GO: merged h2+h1 halves          (chunks 36..51)
    ACC_BIAS(1024, 2)
    gemm_pass<16, 8>(acc, bc, wb + 589824,
                     (t < TT - 1) ? (wb + (size_t)r10 * 16384)
                                  : (wb + 851968 + (size_t)r8 * 16384),
                     h2s, h1s, r16, lane);
    BAR_LGKM_VM4()                                 // B3: h reads done; vmcnt(4)=bc only -> xts landed
    finish_go(acc, c2, sib, h2s, lane, wid);       // writes h2s
  }
  BAR_LGKM()                                       // final h2s visible

  // ---- output projection: out = h2 @ Wout^T + bout     (chunks 52..59)
#pragma unroll
  for (int gl = 0; gl < 2; ++gl)
#pragma unroll
    for (int nb = 0; nb < 2; ++nb) {
      float bv = bls[2048 + (wid << 6) + ((gl * 2 + nb) << 4) + l15];
#pragma unroll
      for (int rb = 0; rb < 4; ++rb) acc[gl][nb][rb] = (f32x4){bv, bv, bv, bv};
    }
  gemm_pass<8, 8>(acc, bc, wb + 851968, wb + 851968, h2s, h2s, r8, lane);

#pragma unroll
  for (int gl = 0; gl < 2; ++gl)
#pragma unroll
    for (int nb = 0; nb < 2; ++nb) {
      int n = (wid << 6) + ((gl * 2 + nb) << 4) + l15;
      if (n < NLAB) {
#pragma unroll
        for (int rb = 0; rb < 4; ++rb)
#pragma unroll
          for (int r = 0; r < 4; ++r) {
            int row = (rb << 4) + ((lane >> 4) << 2) + r;
            out[(size_t)(b0 + row) * NLAB + n] = acc[gl][nb][rb][r];
          }
      }
    }
#undef ACC_BIAS
}

extern "C" void kernel_launch(void* const* d_in, const int* in_sizes, int n_in,
                              void* d_out, int out_size, void* d_ws, size_t ws_size,
                              hipStream_t stream) {
  const int* car_idx    = (const int*)d_in[0];
  const int* region_idx = (const int*)d_in[1];
  const int* poi_idx    = (const int*)d_in[2];
  const int* week_idx   = (const int*)d_in[3];
  const int* time_idx   = (const int*)d_in[4];
  const float* car_emb    = (const float*)d_in[5];
  const float* region_emb = (const float*)d_in[6];
  const float* poi_emb    = (const float*)d_in[7];
  const float* week_emb   = (const float*)d_in[8];
  const float* time_emb   = (const float*)d_in[9];
  const float* Wih0 = (const float*)d_in[10];
  const float* Whh0 = (const float*)d_in[11];
  const float* bih0 = (const float*)d_in[12];
  const float* bhh0 = (const float*)d_in[13];
  const float* Wih1 = (const float*)d_in[14];
  const float* Whh1 = (const float*)d_in[15];
  const float* bih1 = (const float*)d_in[16];
  const float* bhh1 = (const float*)d_in[17];
  const float* Wout = (const float*)d_in[18];
  const float* bout = (const float*)d_in[19];

  // workspace: xfrag (20 MB), weight wall (983040 bf16), bias blob
  unsigned short* xfrag = (unsigned short*)d_ws;       // 10,485,760 bf16
  unsigned short* wallp = xfrag + 10485760;            // 983,040 bf16
  float* bblob = (float*)(wallp + 983040);             // 2,560 f32

  prep_w<<<3850, 256, 0, stream>>>(Wih0, Whh0, bih0, bhh0, Wih1, Whh1, bih1, bhh1,
                                   Wout, bout, wallp, bblob);
  gather_x<<<640, 256, 0, stream>>>(car_idx, region_idx, poi_idx, week_idx, time_idx,
                                    car_emb, region_emb, poi_emb, week_emb, time_emb, xfrag);
  lstm_fused<<<256, 512, 0, stream>>>(xfrag, wallp, bblob, (float*)d_out);
}